// Round 7
// baseline (1111.400 us; speedup 1.0000x reference)
//
#include <hip/hip_runtime.h>
#include <hip/hip_cooperative_groups.h>
#include <math.h>

namespace cg = cooperative_groups;

#define KT 512
#define VW 50257
#define DD 300
#define RR 75
#define DR 375
#define GAMMA 0.010187536f   // KT/VW — uniform gauge factor, cancels in row-normalize
#define SLOTS 8              // hierarchical atomic slots for row sums
#define CB 252               // cooperative blocks (252*200 >= VW), 1 block/CU

typedef _Float16 half8 __attribute__((ext_vector_type(8)));
typedef float f32x4 __attribute__((ext_vector_type(4)));

__device__ __forceinline__ void load_lds16(const void* g, void* l) {
  __builtin_amdgcn_global_load_lds(
      (const __attribute__((address_space(1))) unsigned int*)g,
      (__attribute__((address_space(3))) unsigned int*)l, 16, 0, 0);
}

__device__ inline float block_reduce_sum(float val, float* sbuf) {
  int t = threadIdx.x;
  sbuf[t] = val;
  __syncthreads();
  for (int off = blockDim.x >> 1; off > 0; off >>= 1) {
    if (t < off) sbuf[t] += sbuf[t + off];
    __syncthreads();
  }
  float r = sbuf[0];
  __syncthreads();
  return r;
}

// DPP wave64 reduce-add: result lands in lane 63 (VALU pipe, no LDS traffic)
template <int CTRL>
__device__ __forceinline__ float dpp_add_step(float x) {
  int yi = __builtin_amdgcn_update_dpp(0, __float_as_int(x), CTRL, 0xf, 0xf, false);
  return x + __int_as_float(yi);
}
__device__ __forceinline__ float wave_reduce_add(float x) {
  x = dpp_add_step<0x111>(x);  // row_shr:1
  x = dpp_add_step<0x112>(x);  // row_shr:2
  x = dpp_add_step<0x114>(x);  // row_shr:4
  x = dpp_add_step<0x118>(x);  // row_shr:8
  x = dpp_add_step<0x142>(x);  // row_bcast:15
  x = dpp_add_step<0x143>(x);  // row_bcast:31
  return x;                    // lane 63 = full sum
}

// ---------- We [VW][300] f32 -> We2 [VW][640] fp16 = [hi(300)|pad|lo(300)|pad] ----------
__global__ void prep_We_split(const float* __restrict__ We, _Float16* __restrict__ We2) {
  int v = blockIdx.x, c = threadIdx.x;            // block 320 threads
  float x = (c < DD) ? We[(size_t)v * DD + c] : 0.f;
  _Float16 h = (_Float16)x;
  We2[(size_t)v * 640 + c] = h;
  We2[(size_t)v * 640 + 320 + c] = (_Float16)(x - (float)h);
}

// ---------- Bext_raw [375][300] f32 ----------
__global__ void prep_bext(const float* __restrict__ Wp, const float* __restrict__ MU,
                          float* __restrict__ Bext) {
  int id = blockIdx.x * blockDim.x + threadIdx.x;
  if (id >= DR * DD) return;
  int row = id / DD, d = id - row * DD;
  if (row < DD) {
    Bext[id] = Wp[row * DD + d];
  } else {
    int r = row - DD;
    float s = 0.f;
    for (int j = 0; j < DD; ++j) s += MU[j * RR + r] * Wp[j * DD + d];
    Bext[id] = s;
  }
}

// ---------- Bext2 [384][640] fp16 split (rows>=375 zero) ----------
__global__ void prep_bext_split(const float* __restrict__ BextR, _Float16* __restrict__ Bext2) {
  int r = blockIdx.x, c = threadIdx.x;            // 384 blocks x 320
  float x = (r < DR && c < DD) ? BextR[r * DD + c] : 0.f;
  _Float16 h = (_Float16)x;
  Bext2[(size_t)r * 640 + c] = h;
  Bext2[(size_t)r * 640 + 320 + c] = (_Float16)(x - (float)h);
}

// ---------- anchors -> Ahat2 [512][768] fp16 = [hi(384)|lo(384)], AA ----------
__global__ void prep_anchors(const float* __restrict__ anchors, const float* __restrict__ MU,
                             _Float16* __restrict__ Ahat2, float* __restrict__ AA) {
  __shared__ float a[DD];
  __shared__ float psh[RR];
  __shared__ float red[128];
  __shared__ float inv_sh;
  int k = blockIdx.x, t = threadIdx.x;
  float ss = 0.f;
  for (int d = t; d < DD; d += 128) {
    float x = anchors[k * DD + d];
    a[d] = x;
    ss += x * x;
  }
  ss = block_reduce_sum(ss, red);
  if (t == 0) inv_sh = 1.f / fmaxf(sqrtf(ss), 1e-12f);
  __syncthreads();
  float inv = inv_sh;
  float p2 = 0.f;
  if (t < RR) {
    float p = 0.f;
    for (int j = 0; j < DD; ++j) p += MU[j * RR + t] * a[j];
    p *= inv;
    psh[t] = p;
    p2 = p * p;
  }
  p2 = block_reduce_sum(p2, red);
  _Float16* row = Ahat2 + (size_t)k * 768;
  for (int d = t; d < 384; d += 128) {
    float val = (d < DD) ? a[d] * inv : ((d < DR) ? psh[d - DD] : 0.f);
    _Float16 h = (_Float16)val;
    row[d] = h;
    row[384 + d] = (_Float16)(val - (float)h);
  }
  if (t == 0) AA[k] = 1.f + p2;
}

// ---------- normalize What rows in place: f32 [VW][384] -> fp16 [VW][768], WW ----------
__global__ void prep_words(float* __restrict__ WhatR, float* __restrict__ WW) {
  __shared__ float red[128];
  __shared__ float inv_sh;
  int v = blockIdx.x, t = threadIdx.x;
  float* rowf = WhatR + (size_t)v * 384;
  float x0 = rowf[t];
  float x1 = rowf[t + 128];
  float x2 = (t + 256 < DR) ? rowf[t + 256] : 0.f;
  float ss = x0 * x0 + x1 * x1 + ((t < 44) ? x2 * x2 : 0.f);  // cols < 300
  ss = block_reduce_sum(ss, red);
  if (t == 0) inv_sh = 1.f / fmaxf(sqrtf(ss), 1e-12f);
  __syncthreads();
  float inv = inv_sh;
  x0 *= inv; x1 *= inv; x2 *= inv;
  float p2 = (t >= 44 && t + 256 < DR) ? x2 * x2 : 0.f;       // cols 300..374
  p2 = block_reduce_sum(p2, red);
  _Float16* rowh = (_Float16*)rowf;   // in-place: same 1536B footprint
  _Float16 h0 = (_Float16)x0;
  rowh[t] = h0; rowh[384 + t] = (_Float16)(x0 - (float)h0);
  _Float16 h1 = (_Float16)x1;
  rowh[128 + t] = h1; rowh[512 + t] = (_Float16)(x1 - (float)h1);
  float v2 = (t + 256 < DR) ? x2 : 0.f;
  _Float16 h2 = (_Float16)v2;
  rowh[256 + t] = h2; rowh[640 + t] = (_Float16)(v2 - (float)h2);
  if (t == 0) WW[v] = 1.f + p2;
}

// ---------- MFMA NT GEMM, split-fp16 3-term: A'=[hi|lo|hi], B'=[hi|hi|lo] ----------
// EPI==0: store C f32.  EPI==1: store E = min(exp((2C-AA-WW)/eps), 1)
template <int EPI>
__global__ __launch_bounds__(256) void gemm_mfma(
    const _Float16* __restrict__ Ag, int ldaE,
    const _Float16* __restrict__ Bg, int ldbE,
    float* __restrict__ C, long ldc,
    int M, int N, int KTOT, int SEGL, int mOnX,
    const float* __restrict__ AAv, const float* __restrict__ WWv,
    const float* __restrict__ log_eps_ptr) {
  __shared__ __align__(16) _Float16 As[128 * 64];
  __shared__ __align__(16) _Float16 Bs[128 * 64];
  int t = threadIdx.x, lane = t & 63, w = t >> 6;

  // XCD-chunked bijective swizzle (T1/m204): consecutive logical tiles -> same XCD
  int nwg = gridDim.x * gridDim.y;
  int orig = blockIdx.y * gridDim.x + blockIdx.x;
  int q = nwg >> 3, r8 = nwg & 7;
  int xcd = orig & 7, pos = orig >> 3;
  int wgid = (xcd < r8 ? xcd * (q + 1) : r8 * (q + 1) + (xcd - r8) * q) + pos;
  int bxi = wgid % gridDim.x;
  int byi = wgid / gridDim.x;

  int bm = (mOnX ? bxi : byi) * 128;
  int bn = (mOnX ? byi : bxi) * 128;
  int wm = w >> 1, wn = w & 1;
  f32x4 acc[4][4] = {};
  size_t ldaB = (size_t)ldaE * 2, ldbB = (size_t)ldbE * 2;
  int srow = lane >> 3, sg = lane & 7;
  int lr = lane & 15, kq = lane >> 4;

  for (int k0 = 0; k0 < KTOT; k0 += 64) {
    int ak = (k0 >= 2 * SEGL) ? k0 - 2 * SEGL : k0;
    int bk = (k0 >= SEGL) ? k0 - SEGL : k0;
    size_t akb = (size_t)ak * 2, bkb = (size_t)bk * 2;
#pragma unroll
    for (int qq = 0; qq < 4; ++qq) {
      int iid = w * 4 + qq;
      int r = iid * 8 + srow;
      int gs = sg ^ (r & 7);                 // pre-swizzled source granule
      int gmr = bm + r; if (gmr >= M) gmr = M - 1;
      load_lds16((const char*)Ag + (size_t)gmr * ldaB + akb + (gs << 4),
                 (char*)As + iid * 1024);
      int gnr = bn + r; if (gnr >= N) gnr = N - 1;
      load_lds16((const char*)Bg + (size_t)gnr * ldbB + bkb + (gs << 4),
                 (char*)Bs + iid * 1024);
    }
    __syncthreads();
#pragma unroll
    for (int ks = 0; ks < 2; ++ks) {
      half8 af[4], bf[4];
#pragma unroll
      for (int i = 0; i < 4; ++i) {
        int row = wm * 64 + i * 16 + lr;
        af[i] = *(const half8*)((const char*)As + row * 128 +
                                ((((ks << 2) + kq) ^ (row & 7)) << 4));
        int col = wn * 64 + i * 16 + lr;
        bf[i] = *(const half8*)((const char*)Bs + col * 128 +
                                ((((ks << 2) + kq) ^ (col & 7)) << 4));
      }
#pragma unroll
      for (int i = 0; i < 4; ++i)
#pragma unroll
        for (int j = 0; j < 4; ++j)
          acc[i][j] = __builtin_amdgcn_mfma_f32_16x16x32_f16(af[i], bf[j], acc[i][j], 0, 0, 0);
    }
    __syncthreads();
  }

  float s2e = 0.f;
  if (EPI == 1) {
    float le = log_eps_ptr[0];
    float eps = log1pf(__expf(le)) + 1e-4f;
    s2e = 1.4426950408889634f / eps;   // log2(e)/eps
  }
  int rq = lane >> 4;
#pragma unroll
  for (int i = 0; i < 4; ++i) {
#pragma unroll
    for (int j = 0; j < 4; ++j) {
#pragma unroll
      for (int r = 0; r < 4; ++r) {
        int gm = bm + wm * 64 + i * 16 + rq * 4 + r;
        int gn = bn + wn * 64 + j * 16 + lr;
        if (gm < M && gn < N) {
          float c = acc[i][j][r];
          if (EPI == 0) {
            C[(size_t)gm * ldc + gn] = c;
          } else {
            // E = exp(min(2C-AA-WW,0)/eps) = min(exp2((2C-AA-WW)*s2e), 1)
            float e = exp2f((2.f * c - AAv[gm] - WWv[gn]) * s2e);
            C[(size_t)gm * ldc + gn] = fminf(e, 1.0f);
          }
        }
      }
    }
  }
}

// ---------- Cooperative fused Sinkhorn: E lives in registers across all 20 iterations ----
// 252 blocks x 1024 threads, 1 block/CU. Block owns cols [200b, 200b+200) x all 512 rows.
// Thread t: h=t>>9, r=t&511 owns tile[100] = E[r][200b+100h .. +100).
// Per iter: u=1/rowsum (global slots); colsum via DPP over 64 rows/wave (block-local);
// v=GAMMA/colsum in LDS; rowsum thread-local -> slot atomics; grid.sync.
// Finally beta = tile * u' * v written in place.
__global__ __launch_bounds__(1024, 4) void coop_sinkhorn(float* __restrict__ EB,
                                                         float* __restrict__ Sbuf) {
  cg::grid_group gg = cg::this_grid();
  __shared__ float colp[16][100];
  __shared__ float v_sh[200];
  __shared__ float rowp[512][2];
  int t = threadIdx.x;
  int h = t >> 9, r = t & 511, w = t >> 6;
  int cbase = blockIdx.x * 200 + h * 100;
  float* base = EB + (size_t)r * VW + cbase;
  int slot = blockIdx.x & (SLOTS - 1);
  bool full = (cbase + 100 <= VW);

  float tile[100];
  if (full) {
#pragma unroll
    for (int j = 0; j < 100; ++j) tile[j] = base[j];
  } else {
#pragma unroll
    for (int j = 0; j < 100; ++j) tile[j] = (cbase + j < VW) ? base[j] : 0.f;
  }

  // initial row sums (v = 1) -> Sbuf[0]
  {
    float rs = 0.f;
#pragma unroll
    for (int j = 0; j < 100; ++j) rs += tile[j];
    rowp[r][h] = rs;
    __syncthreads();
    if (t < 512)
      unsafeAtomicAdd(&Sbuf[(size_t)slot * KT + t], rowp[t][0] + rowp[t][1]);
    gg.sync();
  }

  for (int it = 1; it <= 20; ++it) {
    // u[r] = 1/rowsum_{it-1}
    const float* Sp = Sbuf + (size_t)(it - 1) * SLOTS * KT;
    float s = 0.f;
#pragma unroll
    for (int q = 0; q < SLOTS; ++q) s += Sp[q * KT + r];
    float u = 1.0f / fmaxf(s, 1e-35f);

    // colsum partials: per col j, DPP-reduce tile[j]*u over the wave's 64 rows
#pragma unroll
    for (int j = 0; j < 100; ++j) {
      float x = wave_reduce_add(tile[j] * u);
      if ((t & 63) == 63) colp[w][j] = x;
    }
    __syncthreads();
    if (t < 200) {
      int half = t / 100, jj = t - half * 100;
      float cs = 0.f;
#pragma unroll
      for (int q = 0; q < 8; ++q) cs += colp[half * 8 + q][jj];
      v_sh[t] = GAMMA / fmaxf(cs, 1e-35f);
    }
    __syncthreads();

    // rowsum partial: sum_j tile[j] * v[j]
    const float4* vv4 = (const float4*)&v_sh[h * 100];
    float rs = 0.f;
#pragma unroll
    for (int j4 = 0; j4 < 25; ++j4) {
      float4 v4 = vv4[j4];
      rs = fmaf(tile[j4 * 4 + 0], v4.x, rs);
      rs = fmaf(tile[j4 * 4 + 1], v4.y, rs);
      rs = fmaf(tile[j4 * 4 + 2], v4.z, rs);
      rs = fmaf(tile[j4 * 4 + 3], v4.w, rs);
    }
    rowp[r][h] = rs;
    __syncthreads();
    if (t < 512)
      unsafeAtomicAdd(&Sbuf[(size_t)it * SLOTS * KT + slot * KT + t],
                      rowp[t][0] + rowp[t][1]);
    gg.sync();
  }

  // final: u' from Sbuf[20]; beta = tile * u' * v20 (v20 still in v_sh), in place
  {
    const float* Sp = Sbuf + (size_t)20 * SLOTS * KT;
    float s = 0.f;
#pragma unroll
    for (int q = 0; q < SLOTS; ++q) s += Sp[q * KT + r];
    float up = 1.0f / fmaxf(s, 1e-35f);
    if (full) {
#pragma unroll
      for (int j = 0; j < 100; ++j) base[j] = tile[j] * (up * v_sh[h * 100 + j]);
    } else {
#pragma unroll
      for (int j = 0; j < 100; ++j)
        if (cbase + j < VW) base[j] = tile[j] * (up * v_sh[h * 100 + j]);
    }
  }
}

extern "C" void kernel_launch(void* const* d_in, const int* in_sizes, int n_in,
                              void* d_out, int out_size, void* d_ws, size_t ws_size,
                              hipStream_t stream) {
  const float* We = (const float*)d_in[0];
  const float* An = (const float*)d_in[1];
  const float* MU = (const float*)d_in[2];
  const float* Wp = (const float*)d_in[3];
  const float* log_eps = (const float*)d_in[4];
  float* out = (float*)d_out;                    // holds E, then beta

  char* p = (char*)d_ws;
  auto take = [&](size_t b) { char* r = p; p += (b + 255) & ~(size_t)255; return r; };
  _Float16* We2   = (_Float16*)take((size_t)VW * 640 * 2);
  _Float16* Bext2 = (_Float16*)take((size_t)384 * 640 * 2);
  _Float16* Ahat2 = (_Float16*)take((size_t)KT * 768 * 2);
  float* WhatR    = (float*)take((size_t)VW * 384 * 4);  // aliased to What2 fp16 [VW][768]
  float* BextR    = (float*)take((size_t)DR * DD * 4);
  float* AA       = (float*)take(KT * 4);
  float* WW       = (float*)take((size_t)VW * 4);
  float* Sbuf     = (float*)take((size_t)21 * SLOTS * KT * 4);  // 21 sweeps x 8 slots x 512
  _Float16* What2 = (_Float16*)WhatR;

  // zero all sweep accumulators once per launch (part of the captured graph)
  (void)hipMemsetAsync(Sbuf, 0, (size_t)21 * SLOTS * KT * 4, stream);

  prep_We_split<<<VW, 320, 0, stream>>>(We, We2);
  prep_bext<<<(DR * DD + 255) / 256, 256, 0, stream>>>(Wp, MU, BextR);
  prep_bext_split<<<384, 320, 0, stream>>>(BextR, Bext2);
  prep_anchors<<<KT, 128, 0, stream>>>(An, MU, Ahat2, AA);

  // What_raw[v][0..383] = We' @ Bext'^T   (M=VW, N=384, K'=960, SEG=320)
  gemm_mfma<0><<<dim3(3, 393), 256, 0, stream>>>(
      We2, 640, Bext2, 640, WhatR, 384, VW, 384, 960, 320, 0,
      nullptr, nullptr, nullptr);

  prep_words<<<VW, 128, 0, stream>>>(WhatR, WW);

  // E = exp(min(2*Ahat@What^T - AA - WW,0)/eps)   (M=KT, N=VW, K'=1152, SEG=384)
  gemm_mfma<1><<<dim3(4, 393), 256, 0, stream>>>(
      Ahat2, 768, What2, 768, out, VW, KT, VW, 1152, 384, 1,
      AA, WW, log_eps);

  // Entire Sinkhorn + beta write in one cooperative kernel (E in registers)
  void* kargs[] = {(void*)&out, (void*)&Sbuf};
  (void)hipLaunchCooperativeKernel((void*)coop_sinkhorn, dim3(CB), dim3(1024),
                                   kargs, 0, stream);
}